// Round 5
// baseline (76.217 us; speedup 1.0000x reference)
//
#include <hip/hip_runtime.h>

static constexpr int Qq = 64, Nn = 4096, Kk = 512, Cc = 256, Tt = 32768;
static constexpr float kLog2e = 1.4426950408889634f;
static constexpr float kLn2 = 0.6931471805599453f;
static constexpr float kInvCount = 1.0f / 131072.0f;  // B * T
static constexpr int kCols = 131072;                  // B * T

// ---------------------------------------------------------------------------
// recon_part: grid = 512 col-blocks x 8 class-groups = 4096 blocks.
// Block: 256 columns x 32 classes. Thread: 4 cols (float4) x 8 classes,
// all 8 dwordx4 loads in flight. Partial (S,V) per column -> ws planes.
// ---------------------------------------------------------------------------
__global__ __launch_bounds__(256) void recon_part(const float* __restrict__ qp,
                                                  const int* __restrict__ tgt,
                                                  float* __restrict__ splane,
                                                  float* __restrict__ vplane) {
  __shared__ float4 ss4[4 * 64];
  __shared__ float4 vv4[4 * 64];
  const int bid = blockIdx.x;
  const int g = bid & 7;          // class group: classes [32g, 32g+32)
  const int cb = bid >> 3;        // column block 0..511
  const int tid = threadIdx.x;
  const int tq = tid & 63;
  const int cr = tid >> 6;        // wave id: classes 32g+8cr .. +8
  const int col0 = cb * 256;
  const int b = col0 >> 15;
  const int tloc = (col0 & (Tt - 1)) + 4 * tq;
  const float* base = qp + (size_t)b * Cc * Tt + tloc;
  const int4 tg4 = *(const int4*)(tgt + col0 + 4 * tq);
  const int cbase = g * 32 + cr * 8;

  float4 v[8];
#pragma unroll
  for (int i = 0; i < 8; ++i)
    v[i] = *(const float4*)(base + (size_t)(cbase + i) * Tt);

  float s0 = 0.f, s1 = 0.f, s2 = 0.f, s3 = 0.f;
  float V0 = 0.f, V1 = 0.f, V2 = 0.f, V3 = 0.f;
#pragma unroll
  for (int i = 0; i < 8; ++i) {
    int c = cbase + i;
    s0 += __builtin_amdgcn_exp2f(v[i].x * kLog2e);
    s1 += __builtin_amdgcn_exp2f(v[i].y * kLog2e);
    s2 += __builtin_amdgcn_exp2f(v[i].z * kLog2e);
    s3 += __builtin_amdgcn_exp2f(v[i].w * kLog2e);
    V0 = (c == tg4.x) ? v[i].x : V0;
    V1 = (c == tg4.y) ? v[i].y : V1;
    V2 = (c == tg4.z) ? v[i].z : V2;
    V3 = (c == tg4.w) ? v[i].w : V3;
  }
  ss4[cr * 64 + tq] = make_float4(s0, s1, s2, s3);
  vv4[cr * 64 + tq] = make_float4(V0, V1, V2, V3);
  __syncthreads();

  // float index cr*256 + (4tq+comp) == column col0 + local; thread tid owns
  // column col0+tid: sum the 4 wave-partials, store to plane g.
  const float* ssf = (const float*)ss4;
  const float* vvf = (const float*)vv4;
  float S = (ssf[tid] + ssf[256 + tid]) + (ssf[512 + tid] + ssf[768 + tid]);
  float V = (vvf[tid] + vvf[256 + tid]) + (vvf[512 + tid] + vvf[768 + tid]);
  splane[(size_t)g * kCols + col0 + tid] = S;
  vplane[(size_t)g * kCols + col0 + tid] = V;
}

// ---------------------------------------------------------------------------
// recon_merge: 512 blocks x 256. Column sum over 8 groups, ln(S) - V,
// block-reduce -> part[0..511].
// ---------------------------------------------------------------------------
__global__ __launch_bounds__(256) void recon_merge(const float* __restrict__ splane,
                                                   const float* __restrict__ vplane,
                                                   float* __restrict__ part) {
  const int tid = threadIdx.x;
  const int col = blockIdx.x * 256 + tid;
  float S = 0.f, V = 0.f;
#pragma unroll
  for (int g = 0; g < 8; ++g) {
    S += splane[(size_t)g * kCols + col];
    V += vplane[(size_t)g * kCols + col];
  }
  float contrib = kLn2 * __builtin_amdgcn_logf(S) - V;
#pragma unroll
  for (int off = 32; off > 0; off >>= 1) contrib += __shfl_down(contrib, off);
  __shared__ float wsum[4];
  if ((tid & 63) == 0) wsum[tid >> 6] = contrib;
  __syncthreads();
  if (tid == 0) part[blockIdx.x] = (wsum[0] + wsum[1]) + (wsum[2] + wsum[3]);
}

// ---------------------------------------------------------------------------
// VQ: unchanged from R4 (verified). 512 blocks x 32 columns.
// ---------------------------------------------------------------------------
__global__ __launch_bounds__(256) void vq_kernel(const float* __restrict__ ze,
                                                 const float* __restrict__ emb,
                                                 const float* __restrict__ cw,
                                                 float* __restrict__ vqpart) {
  __shared__ __align__(16) float smem[2944];
  float* zs = smem;                                   // [32][68]
  float* e2s = smem + 2176;                           // [512]
  unsigned long long* red2 = (unsigned long long*)(smem + 2688);

  const int tid = threadIdx.x;
  const int vb = blockIdx.x;
  const int b = vb >> 7;
  const int n0 = (vb & 127) << 5;
  const float* zebase = ze + (size_t)b * Qq * Nn + n0;

  for (int idx = tid; idx < 2048; idx += 256) {
    int q = idx >> 5, n = idx & 31;
    zs[n * 68 + q] = zebase[(size_t)q * Nn + n];
  }
  for (int k = tid; k < Kk; k += 256) {
    const float4* row = (const float4*)(emb + (size_t)k * Qq);
    float a = 0.f;
#pragma unroll
    for (int i = 0; i < 16; ++i) {
      float4 f = row[i];
      a += f.x * f.x + f.y * f.y + f.z * f.z + f.w * f.w;
    }
    e2s[k] = a;
  }
  __syncthreads();

  const int ct = tid & 15;
  const int kt = tid >> 4;
  float best[2] = {INFINITY, INFINITY};
  int bestk[2] = {0, 0};

  for (int ch = 0; ch < 8; ++ch) {
    float acc[2][4];
#pragma unroll
    for (int ci = 0; ci < 2; ++ci)
#pragma unroll
      for (int j = 0; j < 4; ++j) acc[ci][j] = 0.f;

    const float* ebase = emb + (size_t)(ch * 64 + kt) * Qq;
#pragma unroll 4
    for (int qc = 0; qc < 16; ++qc) {
      float4 zv[2];
#pragma unroll
      for (int ci = 0; ci < 2; ++ci)
        zv[ci] = *(const float4*)&zs[(ct + 16 * ci) * 68 + 4 * qc];
#pragma unroll
      for (int j = 0; j < 4; ++j) {
        float4 ev = *(const float4*)(ebase + (size_t)j * 16 * Qq + 4 * qc);
#pragma unroll
        for (int ci = 0; ci < 2; ++ci)
          acc[ci][j] += zv[ci].x * ev.x + zv[ci].y * ev.y +
                        zv[ci].z * ev.z + zv[ci].w * ev.w;
      }
    }
#pragma unroll
    for (int j = 0; j < 4; ++j) {
      int k = ch * 64 + kt + 16 * j;
      float e2 = e2s[k];
#pragma unroll
      for (int ci = 0; ci < 2; ++ci) {
        float sc = e2 - 2.0f * acc[ci][j];
        if (sc < best[ci]) { best[ci] = sc; bestk[ci] = k; }
      }
    }
  }

  unsigned long long pk[2];
#pragma unroll
  for (int ci = 0; ci < 2; ++ci) {
    unsigned u = __float_as_uint(best[ci]);
    u = (u & 0x80000000u) ? ~u : (u | 0x80000000u);
    pk[ci] = ((unsigned long long)u << 32) | (unsigned)bestk[ci];
  }
#pragma unroll
  for (int off = 32; off >= 16; off >>= 1) {
#pragma unroll
    for (int ci = 0; ci < 2; ++ci) {
      unsigned long long o = __shfl_down(pk[ci], off);
      pk[ci] = (o < pk[ci]) ? o : pk[ci];
    }
  }
  if ((tid & 63) < 16) {
    int w = tid >> 6;
#pragma unroll
    for (int ci = 0; ci < 2; ++ci) red2[w * 32 + ct * 2 + ci] = pk[ci];
  }
  __syncthreads();

  float val = 0.f;
  if (tid < 32) {
    int cc = tid & 15, ci = tid >> 4;
    unsigned long long mn = red2[cc * 2 + ci];
#pragma unroll
    for (int w = 1; w < 4; ++w) {
      unsigned long long v = red2[w * 32 + cc * 2 + ci];
      mn = (v < mn) ? v : mn;
    }
    int kb = (int)(unsigned)(mn & 0xffffffffull);

    const float4* er = (const float4*)(emb + (size_t)kb * Qq);
    float l2 = 0.f;
#pragma unroll
    for (int i = 0; i < 16; ++i) {
      float4 e4 = er[i];
      float d0 = zs[tid * 68 + 4 * i + 0] - e4.x;
      float d1 = zs[tid * 68 + 4 * i + 1] - e4.y;
      float d2 = zs[tid * 68 + 4 * i + 2] - e4.z;
      float d3 = zs[tid * 68 + 4 * i + 3] - e4.w;
      l2 += d0 * d0 + d1 * d1 + d2 * d2 + d3 * d3;
    }
    float wacc = 0.f;
#pragma unroll
    for (int i = 0; i < 9; ++i) wacc += cw[i];
    if (n0 + tid == Nn - 1) wacc -= cw[0];
    val = 1.25f * l2 * wacc;
  }
#pragma unroll
  for (int off = 32; off > 0; off >>= 1) val += __shfl_down(val, off);
  if (tid == 0) vqpart[blockIdx.x] = val;
}

// ---------------------------------------------------------------------------
// final: sum 1024 partials (512 recon + 512 vq), scale, write scalar.
// ---------------------------------------------------------------------------
__global__ __launch_bounds__(256) void final_kernel(const float* __restrict__ part,
                                                    float* __restrict__ out) {
  const int tid = threadIdx.x;
  float s = part[tid] + part[tid + 256] + part[tid + 512] + part[tid + 768];
#pragma unroll
  for (int off = 32; off > 0; off >>= 1) s += __shfl_down(s, off);
  __shared__ float ws[4];
  if ((tid & 63) == 0) ws[tid >> 6] = s;
  __syncthreads();
  if (tid == 0) out[0] = ((ws[0] + ws[1]) + (ws[2] + ws[3])) * kInvCount;
}

extern "C" void kernel_launch(void* const* d_in, const int* in_sizes, int n_in,
                              void* d_out, int out_size, void* d_ws, size_t ws_size,
                              hipStream_t stream) {
  const float* qp  = (const float*)d_in[0];   // (B, C, T) f32
  const int*   tgt = (const int*)d_in[1];     // (B, T) i32
  const float* ze  = (const float*)d_in[2];   // (B, Q, N) f32
  const float* emb = (const float*)d_in[3];   // (K, Q) f32
  const float* cw  = (const float*)d_in[4];   // (9,) f32
  float* out = (float*)d_out;                 // scalar f32

  float* part = (float*)d_ws;                 // [1024]
  float* splane = part + 2048;                // [8][131072]
  float* vplane = splane + 8 * kCols;         // [8][131072]

  recon_part<<<dim3(4096), dim3(256), 0, stream>>>(qp, tgt, splane, vplane);
  recon_merge<<<dim3(512), dim3(256), 0, stream>>>(splane, vplane, part);
  vq_kernel<<<dim3(512), dim3(256), 0, stream>>>(ze, emb, cw, part + 512);
  final_kernel<<<dim3(1), dim3(256), 0, stream>>>(part, out);
}

// Round 6
// 42.666 us; speedup vs baseline: 1.7864x; 1.7864x over previous
//
#include <hip/hip_runtime.h>
#include <hip/hip_bf16.h>

static constexpr int Qq = 64, Nn = 4096, Kk = 512, Cc = 256, Tt = 32768;
static constexpr float kLog2e = 1.4426950408889634f;
static constexpr float kLn2 = 0.6931471805599453f;
static constexpr float kInvCount = 1.0f / 131072.0f;  // B * T

typedef short bf16x8 __attribute__((ext_vector_type(8)));
typedef float f32x4 __attribute__((ext_vector_type(4)));

static __device__ __forceinline__ ushort bf16bits(float f) {
  __hip_bfloat16 h = __float2bfloat16(f);
  return *(ushort*)&h;
}

// ---------------------------------------------------------------------------
// prep: emb f32 -> bf16 (row-major K x Q) + ||emb_k||^2 f32. 512 threads.
// ---------------------------------------------------------------------------
__global__ __launch_bounds__(64) void prep_kernel(const float* __restrict__ emb,
                                                  ushort* __restrict__ embbf,
                                                  float* __restrict__ e2) {
  const int k = blockIdx.x * 64 + threadIdx.x;   // grid 8 x 64 = 512 codes
  const float4* row = (const float4*)(emb + (size_t)k * Qq);
  uint4* orow = (uint4*)(embbf + (size_t)k * Qq);
  float acc = 0.f;
#pragma unroll
  for (int i = 0; i < 8; ++i) {
    float4 f0 = row[2 * i], f1 = row[2 * i + 1];
    acc += f0.x * f0.x + f0.y * f0.y + f0.z * f0.z + f0.w * f0.w;
    acc += f1.x * f1.x + f1.y * f1.y + f1.z * f1.z + f1.w * f1.w;
    uint4 o;
    o.x = (uint)bf16bits(f0.x) | ((uint)bf16bits(f0.y) << 16);
    o.y = (uint)bf16bits(f0.z) | ((uint)bf16bits(f0.w) << 16);
    o.z = (uint)bf16bits(f1.x) | ((uint)bf16bits(f1.y) << 16);
    o.w = (uint)bf16bits(f1.z) | ((uint)bf16bits(f1.w) << 16);
    orow[i] = o;
  }
  e2[k] = acc;
}

// ---------------------------------------------------------------------------
// recon: unchanged from R4 (attribution). One thread per (b,t) column,
// 8 chunks x 32 dword loads in flight, no max-tracking (absmax 0.0 verified).
// ---------------------------------------------------------------------------
__global__ __launch_bounds__(256) void recon_kernel(const float* __restrict__ qp,
                                                    const int* __restrict__ tgt,
                                                    float* __restrict__ rpart) {
  const int col = blockIdx.x * 256 + threadIdx.x;   // 0..131071
  const int b = col >> 15;
  const int t = col & (Tt - 1);
  const int tg = tgt[col];
  const float* base = qp + (size_t)b * Cc * Tt + t;

  float s0 = 0.f, s1 = 0.f, s2 = 0.f, s3 = 0.f, V = 0.f;
#pragma unroll 1
  for (int c0 = 0; c0 < Cc; c0 += 32) {
    float v[32];
#pragma unroll
    for (int i = 0; i < 32; ++i) v[i] = base[(size_t)(c0 + i) * Tt];
#pragma unroll
    for (int i = 0; i < 32; ++i) {
      float e = __builtin_amdgcn_exp2f(v[i] * kLog2e);
      if ((i & 3) == 0) s0 += e;
      else if ((i & 3) == 1) s1 += e;
      else if ((i & 3) == 2) s2 += e;
      else s3 += e;
      V = (c0 + i == tg) ? v[i] : V;
    }
  }
  float S = (s0 + s1) + (s2 + s3);
  float contrib = kLn2 * __builtin_amdgcn_logf(S) - V;

#pragma unroll
  for (int off = 32; off > 0; off >>= 1) contrib += __shfl_down(contrib, off);
  __shared__ float wsum[4];
  if ((threadIdx.x & 63) == 0) wsum[threadIdx.x >> 6] = contrib;
  __syncthreads();
  if (threadIdx.x == 0)
    rpart[blockIdx.x] = (wsum[0] + wsum[1]) + (wsum[2] + wsum[3]);
}

// ---------------------------------------------------------------------------
// vq (MFMA): 256 blocks x 256 threads; block = 64 columns (one b), all 512
// codes. Wave w owns codes [128w,128w+128). dot via mfma_f32_16x16x32_bf16
// (A = emb_bf16 from global, B = ze_bf16 from LDS transposed tile).
// argmin on e2 - 2*dot (bf16-approx; flips only on near-ties whose l2s are
// ~equal); winner's l2 recomputed EXACTLY in f32 from global ze/emb.
// ---------------------------------------------------------------------------
__global__ __launch_bounds__(256) void vq_kernel(const float* __restrict__ ze,
                                                 const float* __restrict__ emb,
                                                 const ushort* __restrict__ embbf,
                                                 const float* __restrict__ e2g,
                                                 const float* __restrict__ cw,
                                                 float* __restrict__ vqpart) {
  __shared__ __align__(16) ushort zs[64 * 72];      // [n][q] bf16, stride 72
  __shared__ unsigned long long red[4 * 64];        // per-wave per-col argmin

  const int tid = threadIdx.x;
  const int b = blockIdx.x >> 6;
  const int n0 = (blockIdx.x & 63) << 6;
  const float* zebase = ze + (size_t)b * Qq * Nn + n0;

  // stage ze f32 -> bf16 transposed tile
  {
    const int nc = tid & 15;        // 4 consecutive n per thread
    const int q0 = tid >> 4;        // q, +16 per iter
#pragma unroll
    for (int it = 0; it < 4; ++it) {
      int q = q0 + 16 * it;
      float4 v = *(const float4*)(zebase + (size_t)q * Nn + 4 * nc);
      zs[(4 * nc + 0) * 72 + q] = bf16bits(v.x);
      zs[(4 * nc + 1) * 72 + q] = bf16bits(v.y);
      zs[(4 * nc + 2) * 72 + q] = bf16bits(v.z);
      zs[(4 * nc + 3) * 72 + q] = bf16bits(v.w);
    }
  }
  __syncthreads();

  const int w = tid >> 6, lane = tid & 63;
  const int lc = lane & 15;   // A: code row within tile; B/D: col within tile
  const int lg = lane >> 4;   // k-group (8 consecutive k) / D row group

  // preload B fragments: 4 col-tiles x 2 k-steps (k = q)
  bf16x8 bf[4][2];
#pragma unroll
  for (int ct = 0; ct < 4; ++ct)
#pragma unroll
    for (int ks = 0; ks < 2; ++ks)
      bf[ct][ks] = *(const bf16x8*)&zs[(ct * 16 + lc) * 72 + ks * 32 + lg * 8];

  unsigned long long pk[4] = {~0ull, ~0ull, ~0ull, ~0ull};
#pragma unroll 2
  for (int mt = 0; mt < 8; ++mt) {
    const int arow = w * 128 + mt * 16 + lc;        // A-fragment code row
    f32x4 acc[4] = {{0.f, 0.f, 0.f, 0.f}, {0.f, 0.f, 0.f, 0.f},
                    {0.f, 0.f, 0.f, 0.f}, {0.f, 0.f, 0.f, 0.f}};
#pragma unroll
    for (int ks = 0; ks < 2; ++ks) {
      bf16x8 af = *(const bf16x8*)(embbf + (size_t)arow * Qq + ks * 32 + lg * 8);
#pragma unroll
      for (int ct = 0; ct < 4; ++ct)
        acc[ct] = __builtin_amdgcn_mfma_f32_16x16x32_bf16(af, bf[ct][ks],
                                                          acc[ct], 0, 0, 0);
    }
    const int kbase = w * 128 + mt * 16 + lg * 4;   // D rows this lane holds
#pragma unroll
    for (int r = 0; r < 4; ++r) {
      int k = kbase + r;
      float e2v = e2g[k];
#pragma unroll
      for (int ct = 0; ct < 4; ++ct) {
        float sc = e2v - 2.0f * acc[ct][r];
        unsigned u = __float_as_uint(sc);
        u = (u & 0x80000000u) ? ~u : (u | 0x80000000u);
        unsigned long long p = ((unsigned long long)u << 32) | (unsigned)k;
        pk[ct] = (p < pk[ct]) ? p : pk[ct];
      }
    }
  }

  // reduce across the 4 row-groups (lanes sharing lane&15)
#pragma unroll
  for (int ct = 0; ct < 4; ++ct) {
    unsigned long long o = __shfl_xor(pk[ct], 16);
    pk[ct] = (o < pk[ct]) ? o : pk[ct];
    o = __shfl_xor(pk[ct], 32);
    pk[ct] = (o < pk[ct]) ? o : pk[ct];
  }
  if (lane < 16) {
#pragma unroll
    for (int ct = 0; ct < 4; ++ct) red[w * 64 + ct * 16 + lane] = pk[ct];
  }
  __syncthreads();

  if (tid < 64) {   // one lane per column: cross-wave min + exact l2
    unsigned long long mn = red[tid];
#pragma unroll
    for (int ww = 1; ww < 4; ++ww) {
      unsigned long long v = red[ww * 64 + tid];
      mn = (v < mn) ? v : mn;
    }
    int kb = (int)(unsigned)(mn & 0xffffffffull);

    const float* zc = zebase + tid;
    const float* er = emb + (size_t)kb * Qq;
    float l2 = 0.f;
#pragma unroll
    for (int q = 0; q < 64; ++q) {
      float d = zc[(size_t)q * Nn] - er[q];
      l2 += d * d;
    }
    float wacc = 0.f;
#pragma unroll
    for (int i = 0; i < 9; ++i) wacc += cw[i];
    if (n0 + tid == Nn - 1) wacc -= cw[0];   // dropped last timestep tap
    float val = 1.25f * l2 * wacc;           // (1 + GAMMA) * l2 * W_n
#pragma unroll
    for (int off = 32; off > 0; off >>= 1) val += __shfl_down(val, off);
    if (tid == 0) vqpart[blockIdx.x] = val;
  }
}

// ---------------------------------------------------------------------------
// final: sum 768 partials (512 recon + 256 vq), scale, write scalar.
// ---------------------------------------------------------------------------
__global__ __launch_bounds__(256) void final_kernel(const float* __restrict__ part,
                                                    float* __restrict__ out) {
  const int tid = threadIdx.x;
  float s = part[tid] + part[tid + 256] + part[tid + 512];
#pragma unroll
  for (int off = 32; off > 0; off >>= 1) s += __shfl_down(s, off);
  __shared__ float ws[4];
  if ((tid & 63) == 0) ws[tid >> 6] = s;
  __syncthreads();
  if (tid == 0) out[0] = ((ws[0] + ws[1]) + (ws[2] + ws[3])) * kInvCount;
}

extern "C" void kernel_launch(void* const* d_in, const int* in_sizes, int n_in,
                              void* d_out, int out_size, void* d_ws, size_t ws_size,
                              hipStream_t stream) {
  const float* qp  = (const float*)d_in[0];   // (B, C, T) f32
  const int*   tgt = (const int*)d_in[1];     // (B, T) i32
  const float* ze  = (const float*)d_in[2];   // (B, Q, N) f32
  const float* emb = (const float*)d_in[3];   // (K, Q) f32
  const float* cw  = (const float*)d_in[4];   // (9,) f32
  float* out = (float*)d_out;                 // scalar f32

  float* part = (float*)d_ws;                 // [768] used, pad to 1024
  ushort* embbf = (ushort*)(part + 1024);     // [512*64] bf16
  float* e2 = part + 1024 + 16384;            // [512] f32

  prep_kernel<<<dim3(8), dim3(64), 0, stream>>>(emb, embbf, e2);
  recon_kernel<<<dim3(512), dim3(256), 0, stream>>>(qp, tgt, part);
  vq_kernel<<<dim3(256), dim3(256), 0, stream>>>(ze, emb, embbf, e2, cw, part + 512);
  final_kernel<<<dim3(1), dim3(256), 0, stream>>>(part, out);
}

// Round 7
// 31.174 us; speedup vs baseline: 2.4449x; 1.3686x over previous
//
#include <hip/hip_runtime.h>
#include <hip/hip_bf16.h>

static constexpr int Qq = 64, Nn = 4096, Kk = 512, Cc = 256, Tt = 32768;
static constexpr float kLog2e = 1.4426950408889634f;
static constexpr float kLn2 = 0.6931471805599453f;
static constexpr float kInvCount = 1.0f / 131072.0f;  // B * T

typedef short bf16x8 __attribute__((ext_vector_type(8)));
typedef float f32x4 __attribute__((ext_vector_type(4)));

static __device__ __forceinline__ ushort bf16bits(float f) {
  __hip_bfloat16 h = __float2bfloat16(f);
  return *(ushort*)&h;
}

// load 8 consecutive f32 and convert to a bf16x8 MFMA fragment
static __device__ __forceinline__ bf16x8 cvt8(const float* __restrict__ p) {
  float4 a0 = *(const float4*)p;
  float4 a1 = *(const float4*)(p + 4);
  bf16x8 r;
  r[0] = (short)bf16bits(a0.x); r[1] = (short)bf16bits(a0.y);
  r[2] = (short)bf16bits(a0.z); r[3] = (short)bf16bits(a0.w);
  r[4] = (short)bf16bits(a1.x); r[5] = (short)bf16bits(a1.y);
  r[6] = (short)bf16bits(a1.z); r[7] = (short)bf16bits(a1.w);
  return r;
}

// ---------------------------------------------------------------------------
// Fused: bid%3==0 -> vq role (256 blocks, self-contained MFMA argmin+l2);
// else -> recon role (512 blocks, R6-verbatim streaming logsumexp).
// 3 blocks/CU co-resident: vq compute hides under recon's memory stalls.
// ---------------------------------------------------------------------------
__global__ __launch_bounds__(256) void fused_kernel(const float* __restrict__ qp,
                                                    const int* __restrict__ tgt,
                                                    const float* __restrict__ ze,
                                                    const float* __restrict__ emb,
                                                    const float* __restrict__ cw,
                                                    float* __restrict__ part) {
  __shared__ __align__(16) float smem[3456];  // 13824 B
  const int tid = threadIdx.x;
  const int bid = blockIdx.x;

  if (bid % 3 == 0) {
    // ------------------------------ VQ role ------------------------------
    ushort* zs = (ushort*)smem;                              // [64][72] bf16
    float* e2s = smem + 2304;                                // [512]
    unsigned long long* red = (unsigned long long*)(smem + 2816);  // [4][64]

    const int vb = bid / 3;               // 0..255
    const int b = vb >> 6;
    const int n0 = (vb & 63) << 6;
    const float* zebase = ze + (size_t)b * Qq * Nn + n0;

    // stage ze f32 -> bf16 transposed tile zs[n][q]
    {
      const int nc = tid & 15;
      const int q0 = tid >> 4;
#pragma unroll
      for (int it = 0; it < 4; ++it) {
        int q = q0 + 16 * it;
        float4 v = *(const float4*)(zebase + (size_t)q * Nn + 4 * nc);
        zs[(4 * nc + 0) * 72 + q] = bf16bits(v.x);
        zs[(4 * nc + 1) * 72 + q] = bf16bits(v.y);
        zs[(4 * nc + 2) * 72 + q] = bf16bits(v.z);
        zs[(4 * nc + 3) * 72 + q] = bf16bits(v.w);
      }
    }
    // ||emb_k||^2 into LDS (emb is 128 KB, L2-resident)
    for (int k = tid; k < Kk; k += 256) {
      const float4* row = (const float4*)(emb + (size_t)k * Qq);
      float a = 0.f;
#pragma unroll
      for (int i = 0; i < 16; ++i) {
        float4 f = row[i];
        a += f.x * f.x + f.y * f.y + f.z * f.z + f.w * f.w;
      }
      e2s[k] = a;
    }
    __syncthreads();

    const int w = tid >> 6, lane = tid & 63;
    const int lc = lane & 15;
    const int lg = lane >> 4;

    bf16x8 bfr[4][2];
#pragma unroll
    for (int ct = 0; ct < 4; ++ct)
#pragma unroll
      for (int ks = 0; ks < 2; ++ks)
        bfr[ct][ks] = *(const bf16x8*)&zs[(ct * 16 + lc) * 72 + ks * 32 + lg * 8];

    unsigned long long pk[4] = {~0ull, ~0ull, ~0ull, ~0ull};
#pragma unroll 2
    for (int mt = 0; mt < 8; ++mt) {
      const int arow = w * 128 + mt * 16 + lc;
      const float* ap = emb + (size_t)arow * Qq;
      f32x4 acc[4] = {{0.f, 0.f, 0.f, 0.f}, {0.f, 0.f, 0.f, 0.f},
                      {0.f, 0.f, 0.f, 0.f}, {0.f, 0.f, 0.f, 0.f}};
#pragma unroll
      for (int ks = 0; ks < 2; ++ks) {
        bf16x8 af = cvt8(ap + ks * 32 + lg * 8);
#pragma unroll
        for (int ct = 0; ct < 4; ++ct)
          acc[ct] = __builtin_amdgcn_mfma_f32_16x16x32_bf16(af, bfr[ct][ks],
                                                            acc[ct], 0, 0, 0);
      }
      const int kbase = w * 128 + mt * 16 + lg * 4;
#pragma unroll
      for (int r = 0; r < 4; ++r) {
        int k = kbase + r;
        float e2v = e2s[k];
#pragma unroll
        for (int ct = 0; ct < 4; ++ct) {
          float sc = e2v - 2.0f * acc[ct][r];
          unsigned u = __float_as_uint(sc);
          u = (u & 0x80000000u) ? ~u : (u | 0x80000000u);
          unsigned long long p = ((unsigned long long)u << 32) | (unsigned)k;
          pk[ct] = (p < pk[ct]) ? p : pk[ct];
        }
      }
    }

#pragma unroll
    for (int ct = 0; ct < 4; ++ct) {
      unsigned long long o = __shfl_xor(pk[ct], 16);
      pk[ct] = (o < pk[ct]) ? o : pk[ct];
      o = __shfl_xor(pk[ct], 32);
      pk[ct] = (o < pk[ct]) ? o : pk[ct];
    }
    if (lane < 16) {
#pragma unroll
      for (int ct = 0; ct < 4; ++ct) red[w * 64 + ct * 16 + lane] = pk[ct];
    }
    __syncthreads();

    if (tid < 64) {   // one lane per column: cross-wave min + exact f32 l2
      unsigned long long mn = red[tid];
#pragma unroll
      for (int ww = 1; ww < 4; ++ww) {
        unsigned long long v = red[ww * 64 + tid];
        mn = (v < mn) ? v : mn;
      }
      int kb = (int)(unsigned)(mn & 0xffffffffull);

      const float* zc = zebase + tid;
      const float* er = emb + (size_t)kb * Qq;
      float l2 = 0.f;
#pragma unroll
      for (int q = 0; q < 64; ++q) {
        float d = zc[(size_t)q * Nn] - er[q];
        l2 += d * d;
      }
      float wacc = 0.f;
#pragma unroll
      for (int i = 0; i < 9; ++i) wacc += cw[i];
      if (n0 + tid == Nn - 1) wacc -= cw[0];   // dropped last timestep tap
      float val = 1.25f * l2 * wacc;           // (1 + GAMMA) * l2 * W_n
#pragma unroll
      for (int off = 32; off > 0; off >>= 1) val += __shfl_down(val, off);
      if (tid == 0) part[512 + vb] = val;
    }
  } else {
    // ----------------------------- recon role -----------------------------
    const int rb = bid - bid / 3 - 1;               // 0..511
    const int col = rb * 256 + tid;                 // 0..131071
    const int b = col >> 15;
    const int t = col & (Tt - 1);
    const int tg = tgt[col];
    const float* base = qp + (size_t)b * Cc * Tt + t;

    float s0 = 0.f, s1 = 0.f, s2 = 0.f, s3 = 0.f, V = 0.f;
#pragma unroll 1
    for (int c0 = 0; c0 < Cc; c0 += 32) {
      float v[32];
#pragma unroll
      for (int i = 0; i < 32; ++i) v[i] = base[(size_t)(c0 + i) * Tt];
#pragma unroll
      for (int i = 0; i < 32; ++i) {
        float e = __builtin_amdgcn_exp2f(v[i] * kLog2e);
        if ((i & 3) == 0) s0 += e;
        else if ((i & 3) == 1) s1 += e;
        else if ((i & 3) == 2) s2 += e;
        else s3 += e;
        V = (c0 + i == tg) ? v[i] : V;
      }
    }
    float S = (s0 + s1) + (s2 + s3);
    float contrib = kLn2 * __builtin_amdgcn_logf(S) - V;

#pragma unroll
    for (int off = 32; off > 0; off >>= 1) contrib += __shfl_down(contrib, off);
    float* wsum = smem + 3328;
    if ((tid & 63) == 0) wsum[tid >> 6] = contrib;
    __syncthreads();
    if (tid == 0) part[rb] = (wsum[0] + wsum[1]) + (wsum[2] + wsum[3]);
  }
}

// ---------------------------------------------------------------------------
// final: sum 768 partials (512 recon + 256 vq), scale, write scalar.
// ---------------------------------------------------------------------------
__global__ __launch_bounds__(256) void final_kernel(const float* __restrict__ part,
                                                    float* __restrict__ out) {
  const int tid = threadIdx.x;
  float s = part[tid] + part[tid + 256] + part[tid + 512];
#pragma unroll
  for (int off = 32; off > 0; off >>= 1) s += __shfl_down(s, off);
  __shared__ float ws[4];
  if ((tid & 63) == 0) ws[tid >> 6] = s;
  __syncthreads();
  if (tid == 0) out[0] = ((ws[0] + ws[1]) + (ws[2] + ws[3])) * kInvCount;
}

extern "C" void kernel_launch(void* const* d_in, const int* in_sizes, int n_in,
                              void* d_out, int out_size, void* d_ws, size_t ws_size,
                              hipStream_t stream) {
  const float* qp  = (const float*)d_in[0];   // (B, C, T) f32
  const int*   tgt = (const int*)d_in[1];     // (B, T) i32
  const float* ze  = (const float*)d_in[2];   // (B, Q, N) f32
  const float* emb = (const float*)d_in[3];   // (K, Q) f32
  const float* cw  = (const float*)d_in[4];   // (9,) f32
  float* out = (float*)d_out;                 // scalar f32
  float* part = (float*)d_ws;                 // [768] floats, all written

  fused_kernel<<<dim3(768), dim3(256), 0, stream>>>(qp, tgt, ze, emb, cw, part);
  final_kernel<<<dim3(1), dim3(256), 0, stream>>>(part, out);
}